// Round 1
// baseline (350.479 us; speedup 1.0000x reference)
//
#include <hip/hip_runtime.h>
#include <math.h>

#define BB 2
#define NN 256
#define EE 512
#define PP 256
#define DD 128
#define TT 8
#define KK 8
#define HDIM 256

// workspace offsets (floats)
#define WS_G      0          // B*E*K = 8192
#define WS_C0     8192       // 1 (+pad)
#define WS_EF0    8256       // B*E*D = 131072   (later reused for ete)
#define WS_U1     139328     // B*E*HD = 262144  (later reused for U2)
#define WS_V      401472     // B*N*HD = 131072
#define WS_HW     532544     // B*E*N = 262144   (later reused for Hw2)
#define WS_EDGEF  794688     // B*E*D = 131072
#define WS_ETYPE  925760     // B*E*T = 8192
#define WS_AGF    933952     // B*N*3D = 196608
#define WS_Q2     1130560    // B*N*D = 65536
#define WS_K2     1196096    // 65536
#define WS_V2     1261632    // 65536
// total 1327168 floats = 5.31 MB

__device__ inline unsigned rotl32(unsigned x, int d){ return (x<<d)|(x>>(32-d)); }

__device__ inline float bits_to_gumbel(unsigned bits){
  float f = __uint_as_float((bits>>9)|0x3f800000u) - 1.0f;
  const float minv = 1e-6f;
  const float maxv = 1.0f - 1e-6f;
  float u = f*(maxv-minv) + minv;
  u = fmaxf(minv, u);
  return -logf(-logf(u));
}

// K1: threefry2x32-20 gumbel noise (matches jax.random.uniform(key(42),(2,512,8)))
// plus c0 = relu(b1)@W2 + b2 (second-MLP value at zero input)
__global__ void gumbel_kernel(float* g, float* c0, const float* w_b1,
                              const float* w_W2, const float* w_b2){
  int j = blockIdx.x*blockDim.x + threadIdx.x;
  if (j < 4096) {
    const unsigned k0=0u, k1=42u;
    const unsigned ks2 = k0^k1^0x1BD11BDAu;
    unsigned x0 = (unsigned)j, x1 = (unsigned)j + 4096u;
    const int r0[4]={13,15,26,6}, r1[4]={17,29,16,24};
    x0 += k0; x1 += k1;
    #pragma unroll
    for(int i=0;i<4;i++){ x0+=x1; x1=rotl32(x1,r0[i]); x1^=x0; }
    x0+=k1; x1+=ks2+1u;
    #pragma unroll
    for(int i=0;i<4;i++){ x0+=x1; x1=rotl32(x1,r1[i]); x1^=x0; }
    x0+=ks2; x1+=k0+2u;
    #pragma unroll
    for(int i=0;i<4;i++){ x0+=x1; x1=rotl32(x1,r0[i]); x1^=x0; }
    x0+=k0; x1+=k1+3u;
    #pragma unroll
    for(int i=0;i<4;i++){ x0+=x1; x1=rotl32(x1,r1[i]); x1^=x0; }
    x0+=k1; x1+=ks2+4u;
    #pragma unroll
    for(int i=0;i<4;i++){ x0+=x1; x1=rotl32(x1,r0[i]); x1^=x0; }
    x0+=ks2; x1+=k0+5u;
    g[j]        = bits_to_gumbel(x0);
    g[j+4096]   = bits_to_gumbel(x1);
  }
  if (blockIdx.x==0 && threadIdx.x==0){
    float s = 0.f;
    for (int h=0;h<HDIM;h++) s += fmaxf(w_b1[h],0.f)*w_W2[h];
    c0[0] = s + w_b2[0];
  }
}

// K2: ef_init[b,e,:] = sum_n H*af ; edge_type[b,e,:] = sum_n H*at
__global__ void incidence_kernel(const float* Hm, const float* af, const float* at,
                                 float* ef0, float* etype){
  int be = blockIdx.x;
  int d  = threadIdx.x;           // 128
  int b  = be / EE;
  const float* Hrow = Hm + (size_t)be*NN;
  float acc = 0.f, acct = 0.f;
  for (int n=0;n<NN;n++){
    float hv = Hrow[n];
    if (hv != 0.f) {                       // wave-uniform branch
      acc += af[((size_t)b*NN+n)*DD + d];
      if (d < TT) acct += at[((size_t)b*NN+n)*TT + d];
    }
  }
  ef0[(size_t)be*DD+d] = acc;
  if (d < TT) etype[(size_t)be*TT+d] = acct;
}

// K3: dst[row,h] = src[row,:]@W(128x256 slice) + bias[h]
__global__ void rowmlp_kernel(const float* src, const float* W, const float* bias, float* dst){
  __shared__ float s[DD];
  int row = blockIdx.x;
  int h = threadIdx.x;            // 256
  if (h < DD) s[h] = src[(size_t)row*DD + h];
  __syncthreads();
  float acc = bias ? bias[h] : 0.f;
  #pragma unroll 8
  for (int i=0;i<DD;i++) acc += s[i]*W[(size_t)i*HDIM + h];
  dst[(size_t)row*HDIM + h] = acc;
}

// K4: ew = sum_h relu(U1+V)*W2 + b2 ; Hw = softmax(ew*H, axis=n)*H
__global__ void ew_softmax_kernel(const float* U1, const float* Vm, const float* Hm,
                                  const float* w_W2, const float* w_b2, float* Hw){
  __shared__ float u[HDIM];
  __shared__ float w2[HDIM];
  __shared__ float red[256];
  int be = blockIdx.x;
  int b = be / EE;
  int n = threadIdx.x;            // 256
  u[n]  = U1[(size_t)be*HDIM + n];
  w2[n] = w_W2[n];
  __syncthreads();
  const float4* Vrow = (const float4*)(Vm + ((size_t)b*NN + n)*HDIM);
  float acc = 0.f;
  #pragma unroll 4
  for (int i=0;i<HDIM/4;i++){
    float4 v = Vrow[i];
    acc += fmaxf(u[4*i+0]+v.x,0.f)*w2[4*i+0];
    acc += fmaxf(u[4*i+1]+v.y,0.f)*w2[4*i+1];
    acc += fmaxf(u[4*i+2]+v.z,0.f)*w2[4*i+2];
    acc += fmaxf(u[4*i+3]+v.w,0.f)*w2[4*i+3];
  }
  float ew = acc + w_b2[0];
  float hv = Hm[(size_t)be*NN + n];
  float x = (hv != 0.f) ? ew : 0.f;
  red[n] = x; __syncthreads();
  for (int s=128;s>0;s>>=1){ if (n<s) red[n]=fmaxf(red[n],red[n+s]); __syncthreads(); }
  float m = red[0]; __syncthreads();
  float p = expf(x - m);
  red[n] = p; __syncthreads();
  for (int s=128;s>0;s>>=1){ if (n<s) red[n]+=red[n+s]; __syncthreads(); }
  float denom = red[0];
  Hw[(size_t)be*NN+n] = (hv!=0.f) ? p/denom : 0.f;
}

// K5: out[b,e,:] = sum_n Wgt[b,e,n]*af[b,n,:]
__global__ void aggregate_kernel(const float* Wgt, const float* af, float* outp){
  int be = blockIdx.x; int d = threadIdx.x; int b = be/EE;
  const float* wrow = Wgt + (size_t)be*NN;
  float acc = 0.f;
  for (int n=0;n<NN;n++){
    float w = wrow[n];
    if (w != 0.f) acc += w*af[((size_t)b*NN+n)*DD + d];   // wave-uniform skip
  }
  outp[(size_t)be*DD + d] = acc;
}

// K6: typed edge embedding: logits/factor MLPs, gumbel softmax, ete = (f*dist)@type_emb
__global__ void type_kernel(const float* edgef, const float* etype, const float* g,
                            const float* d_W1, const float* d_b1, const float* d_W2, const float* d_b2,
                            const float* f_W1, const float* f_b1, const float* f_W2, const float* f_b2,
                            const float* type_emb, float* ete){
  __shared__ float et[DD+TT];
  __shared__ float hd_[HDIM];
  __shared__ float red[256];
  __shared__ float z[KK];
  __shared__ float pz[KK];
  __shared__ float fd[KK];
  __shared__ float factor_s;
  int be = blockIdx.x; int t = threadIdx.x;   // 256
  if (t < DD) et[t] = edgef[(size_t)be*DD+t];
  else if (t < DD+TT) et[t] = etype[(size_t)be*TT + (t-DD)];
  __syncthreads();
  float ad = d_b1[t], afv = f_b1[t];
  for (int i=0;i<DD+TT;i++){
    float x = et[i];
    ad  += x*d_W1[(size_t)i*HDIM+t];
    afv += x*f_W1[(size_t)i*HDIM+t];
  }
  hd_[t] = fmaxf(ad, 0.f);
  float hfr = fmaxf(afv, 0.f);
  red[t] = hfr * f_W2[t]; __syncthreads();
  for (int s=128;s>0;s>>=1){ if (t<s) red[t]+=red[t+s]; __syncthreads(); }
  if (t==0) factor_s = 1.f/(1.f+expf(-(red[0]+f_b2[0])));
  __syncthreads();
  if (t < KK){
    float lk = d_b2[t];
    for (int h=0;h<HDIM;h++) lk += hd_[h]*d_W2[(size_t)h*KK + t];
    z[t] = (lk + g[(size_t)be*KK + t]) * 2.0f;   // /tau, tau=0.5
  }
  __syncthreads();
  if (t < KK){
    float m = z[0];
    for (int k=1;k<KK;k++) m = fmaxf(m, z[k]);
    pz[t] = expf(z[t]-m);
  }
  __syncthreads();
  if (t < KK){
    float s = 0.f;
    for (int k=0;k<KK;k++) s += pz[k];
    fd[t] = factor_s * pz[t]/s;
  }
  __syncthreads();
  if (t < DD){
    float acc=0.f;
    for (int k=0;k<KK;k++) acc += fd[k]*type_emb[(size_t)k*DD+t];
    ete[(size_t)be*DD+t]=acc;
  }
}

// K8: raw2 (masked MLP, c0 for H=0), leaky relu, full softmax over n, *H
__global__ void hw2_softmax_kernel(const float* U2, const float* Vm, const float* Hm,
                                   const float* w_W2, const float* w_b2, const float* c0p,
                                   float* Hw2){
  __shared__ float u[HDIM];
  __shared__ float w2[HDIM];
  __shared__ float red[256];
  int be = blockIdx.x; int b = be/EE; int n = threadIdx.x;
  u[n]  = U2[(size_t)be*HDIM+n];
  w2[n] = w_W2[n];
  __syncthreads();
  float hv = Hm[(size_t)be*NN+n];
  float raw;
  if (hv != 0.f){
    const float4* Vrow = (const float4*)(Vm + ((size_t)b*NN+n)*HDIM);
    float acc=0.f;
    #pragma unroll 4
    for (int i=0;i<HDIM/4;i++){
      float4 v=Vrow[i];
      acc += fmaxf(u[4*i+0]+v.x,0.f)*w2[4*i+0];
      acc += fmaxf(u[4*i+1]+v.y,0.f)*w2[4*i+1];
      acc += fmaxf(u[4*i+2]+v.z,0.f)*w2[4*i+2];
      acc += fmaxf(u[4*i+3]+v.w,0.f)*w2[4*i+3];
    }
    raw = acc + w_b2[0];
  } else {
    raw = c0p[0];
  }
  float x = raw>0.f ? raw : 0.01f*raw;     // leaky relu
  red[n]=x; __syncthreads();
  for (int s=128;s>0;s>>=1){ if (n<s) red[n]=fmaxf(red[n],red[n+s]); __syncthreads(); }
  float m = red[0]; __syncthreads();
  float p = expf(x-m);
  red[n]=p; __syncthreads();
  for (int s=128;s>0;s>>=1){ if (n<s) red[n]+=red[n+s]; __syncthreads(); }
  float denom = red[0];
  Hw2[(size_t)be*NN+n] = (hv!=0.f) ? p/denom : 0.f;
}

// K9: msg[b,n,f] = sum_e Hw2[b,e,n]*[edgef|ete][b,e,f]; agent_feat = [msg, af]
__global__ void msg_kernel(const float* Hw2, const float* edgef, const float* ete,
                           const float* af, float* agf){
  int bn = blockIdx.x; int b = bn/NN; int n = bn%NN; int f = threadIdx.x; // 256
  float acc = 0.f;
  const float* src = (f < DD) ? (edgef + f) : (ete + (f - DD));
  for (int e=0;e<EE;e++){
    float w = Hw2[((size_t)b*EE+e)*NN + n];
    if (w != 0.f) acc += w * src[((size_t)b*EE+e)*DD];   // wave-uniform skip
  }
  agf[(size_t)bn*(3*DD)+f] = acc;
  if (f < DD) agf[(size_t)bn*(3*DD) + 2*DD + f] = af[(size_t)bn*DD + f];
}

// K10a: q2 = (agf@q_W+q_b)@iq_W+iq_b
__global__ void q2_kernel(const float* agf, const float* q_W, const float* q_b,
                          const float* iq_W, const float* iq_b, float* q2){
  __shared__ float row[3*DD];
  __shared__ float Qs[DD];
  int bn = blockIdx.x; int d = threadIdx.x; // 128
  for (int i=d;i<3*DD;i+=DD) row[i]=agf[(size_t)bn*3*DD+i];
  __syncthreads();
  float q = q_b[d];
  #pragma unroll 8
  for (int i=0;i<3*DD;i++) q += row[i]*q_W[(size_t)i*DD+d];
  Qs[d]=q; __syncthreads();
  float v = iq_b[d];
  #pragma unroll 8
  for (int i=0;i<DD;i++) v += Qs[i]*iq_W[(size_t)i*DD+d];
  q2[(size_t)bn*DD+d]=v;
}

// K10b: k2, v2 from polyline features
__global__ void kv_kernel(const float* pf,
                          const float* k_W,const float* k_b,const float* ik_W,const float* ik_b,
                          const float* v_W,const float* v_b,const float* iv_W,const float* iv_b,
                          float* k2, float* v2){
  __shared__ float row[DD];
  __shared__ float tmp[DD];
  int bp=blockIdx.x; int d=threadIdx.x;   // 128
  row[d]=pf[(size_t)bp*DD+d]; __syncthreads();
  float kk=k_b[d];
  #pragma unroll 8
  for(int i=0;i<DD;i++) kk+=row[i]*k_W[(size_t)i*DD+d];
  tmp[d]=kk; __syncthreads();
  float kv=ik_b[d];
  #pragma unroll 8
  for(int i=0;i<DD;i++) kv+=tmp[i]*ik_W[(size_t)i*DD+d];
  k2[(size_t)bp*DD+d]=kv; __syncthreads();
  float vv=v_b[d];
  #pragma unroll 8
  for(int i=0;i<DD;i++) vv+=row[i]*v_W[(size_t)i*DD+d];
  tmp[d]=vv; __syncthreads();
  float v2v=iv_b[d];
  #pragma unroll 8
  for(int i=0;i<DD;i++) v2v+=tmp[i]*iv_W[(size_t)i*DD+d];
  v2[(size_t)bp*DD+d]=v2v;
}

// K10c: 4-head cross attention + output proj -> polyline_new
__global__ void attn_kernel(const float* q2, const float* k2, const float* v2,
                            const float* op_W, const float* op_b, float* pnew){
  __shared__ float qr[DD];
  __shared__ float att[4*PP];
  __shared__ float red[256];
  __shared__ float o_lds[DD];
  int bn = blockIdx.x; int b = bn/NN; int t = threadIdx.x; // 256 (= p index)
  if (t<DD) qr[t]=q2[(size_t)bn*DD+t];
  __syncthreads();
  const float scale = 0.17677669529663687f;  // 1/sqrt(32)
  const float* krow = k2 + ((size_t)b*PP + t)*DD;
  for (int h=0;h<4;h++){
    float s=0.f;
    #pragma unroll 8
    for (int j=0;j<32;j++) s += qr[h*32+j]*krow[h*32+j];
    att[h*PP+t]=s*scale;
  }
  __syncthreads();
  for (int h=0;h<4;h++){
    float x = att[h*PP+t];
    red[t]=x; __syncthreads();
    for (int s=128;s>0;s>>=1){ if(t<s) red[t]=fmaxf(red[t],red[t+s]); __syncthreads(); }
    float m=red[0]; __syncthreads();
    float p=expf(x-m);
    red[t]=p; __syncthreads();
    for (int s=128;s>0;s>>=1){ if(t<s) red[t]+=red[t+s]; __syncthreads(); }
    float dn=red[0]; __syncthreads();
    att[h*PP+t]=p/dn;
    __syncthreads();
  }
  if (t < DD){
    float acc=0.f; int h=t>>5;
    for (int p=0;p<PP;p++) acc += att[h*PP+p]*v2[((size_t)b*PP+p)*DD + t];
    o_lds[t]=acc;
  }
  __syncthreads();
  if (t < DD){
    float pn=op_b[t];
    #pragma unroll 8
    for (int i=0;i<DD;i++) pn += o_lds[i]*op_W[(size_t)i*DD+t];
    pnew[(size_t)bn*DD+t]=pn;
  }
}

// K11: agent_new = MLP([agf, pnew], o_*)
__global__ void final_kernel(const float* agf, const float* pnew,
                             const float* o_W1,const float* o_b1,
                             const float* o_W2,const float* o_b2, float* anew){
  __shared__ float x[4*DD];
  __shared__ float hid[HDIM];
  int bn=blockIdx.x; int t=threadIdx.x;  // 256
  x[t] = agf[(size_t)bn*3*DD+t];
  int i2 = t+256;
  x[i2] = (i2 < 3*DD) ? agf[(size_t)bn*3*DD+i2] : pnew[(size_t)bn*DD + (i2-3*DD)];
  __syncthreads();
  float acc=o_b1[t];
  #pragma unroll 8
  for (int i=0;i<4*DD;i++) acc += x[i]*o_W1[(size_t)i*HDIM+t];
  hid[t]=fmaxf(acc,0.f);
  __syncthreads();
  if (t<DD){
    float outv=o_b2[t];
    #pragma unroll 8
    for (int h=0;h<HDIM;h++) outv += hid[h]*o_W2[(size_t)h*DD+t];
    anew[(size_t)bn*DD+t]=outv;
  }
}

extern "C" void kernel_launch(void* const* d_in, const int* in_sizes, int n_in,
                              void* d_out, int out_size, void* d_ws, size_t ws_size,
                              hipStream_t stream) {
  const float* af       = (const float*)d_in[0];
  const float* at       = (const float*)d_in[1];
  const float* pf       = (const float*)d_in[2];
  const float* Hm       = (const float*)d_in[3];
  const float* type_emb = (const float*)d_in[4];
  const float* w_W1 = (const float*)d_in[5];
  const float* w_b1 = (const float*)d_in[6];
  const float* w_W2 = (const float*)d_in[7];
  const float* w_b2 = (const float*)d_in[8];
  const float* d_W1 = (const float*)d_in[9];
  const float* d_b1 = (const float*)d_in[10];
  const float* d_W2 = (const float*)d_in[11];
  const float* d_b2 = (const float*)d_in[12];
  const float* f_W1 = (const float*)d_in[13];
  const float* f_b1 = (const float*)d_in[14];
  const float* f_W2 = (const float*)d_in[15];
  const float* f_b2 = (const float*)d_in[16];
  const float* o_W1 = (const float*)d_in[17];
  const float* o_b1 = (const float*)d_in[18];
  const float* o_W2 = (const float*)d_in[19];
  const float* o_b2 = (const float*)d_in[20];
  const float* q_W  = (const float*)d_in[21];
  const float* q_b  = (const float*)d_in[22];
  const float* k_W  = (const float*)d_in[23];
  const float* k_b  = (const float*)d_in[24];
  const float* v_W  = (const float*)d_in[25];
  const float* v_b  = (const float*)d_in[26];
  const float* iq_W = (const float*)d_in[27];
  const float* iq_b = (const float*)d_in[28];
  const float* ik_W = (const float*)d_in[29];
  const float* ik_b = (const float*)d_in[30];
  const float* iv_W = (const float*)d_in[31];
  const float* iv_b = (const float*)d_in[32];
  const float* op_W = (const float*)d_in[33];
  const float* op_b = (const float*)d_in[34];

  float* ws   = (float*)d_ws;
  float* out  = (float*)d_out;
  float* anew = out;                 // (B,N,D)
  float* pnew = out + BB*NN*DD;      // (B,N,D)

  gumbel_kernel<<<16,256,0,stream>>>(ws+WS_G, ws+WS_C0, w_b1, w_W2, w_b2);
  incidence_kernel<<<BB*EE,128,0,stream>>>(Hm, af, at, ws+WS_EF0, ws+WS_ETYPE);
  rowmlp_kernel<<<BB*EE,256,0,stream>>>(ws+WS_EF0, w_W1,          w_b1,    ws+WS_U1);
  rowmlp_kernel<<<BB*NN,256,0,stream>>>(af,        w_W1 + DD*HDIM, nullptr, ws+WS_V);
  ew_softmax_kernel<<<BB*EE,256,0,stream>>>(ws+WS_U1, ws+WS_V, Hm, w_W2, w_b2, ws+WS_HW);
  aggregate_kernel<<<BB*EE,128,0,stream>>>(ws+WS_HW, af, ws+WS_EDGEF);
  type_kernel<<<BB*EE,256,0,stream>>>(ws+WS_EDGEF, ws+WS_ETYPE, ws+WS_G,
                                      d_W1,d_b1,d_W2,d_b2, f_W1,f_b1,f_W2,f_b2,
                                      type_emb, ws+WS_EF0 /*ete*/);
  rowmlp_kernel<<<BB*EE,256,0,stream>>>(ws+WS_EF0, w_W1, w_b1, ws+WS_U1 /*U2*/);
  hw2_softmax_kernel<<<BB*EE,256,0,stream>>>(ws+WS_U1, ws+WS_V, Hm, w_W2, w_b2,
                                             ws+WS_C0, ws+WS_HW /*Hw2*/);
  msg_kernel<<<BB*NN,256,0,stream>>>(ws+WS_HW, ws+WS_EDGEF, ws+WS_EF0, af, ws+WS_AGF);
  q2_kernel<<<BB*NN,128,0,stream>>>(ws+WS_AGF, q_W,q_b, iq_W,iq_b, ws+WS_Q2);
  kv_kernel<<<BB*PP,128,0,stream>>>(pf, k_W,k_b, ik_W,ik_b, v_W,v_b, iv_W,iv_b,
                                    ws+WS_K2, ws+WS_V2);
  attn_kernel<<<BB*NN,256,0,stream>>>(ws+WS_Q2, ws+WS_K2, ws+WS_V2, op_W, op_b, pnew);
  final_kernel<<<BB*NN,256,0,stream>>>(ws+WS_AGF, pnew, o_W1,o_b1,o_W2,o_b2, anew);
}

// Round 2
// 210.152 us; speedup vs baseline: 1.6677x; 1.6677x over previous
//
#include <hip/hip_runtime.h>
#include <math.h>

#define BB 2
#define NN 256
#define EE 512
#define PP 256
#define DD 128
#define TT 8
#define KK 8
#define HDIM 256

// workspace offsets (floats)
#define WS_G      0          // B*E*K = 8192
#define WS_C0     8192       // 1 (+pad)
#define WS_EF0    8256       // B*E*D = 131072   (later reused for ete)
#define WS_U1     139328     // B*E*HD = 262144  (later reused for U2)
#define WS_V      401472     // B*N*HD = 131072
#define WS_HW     532544     // B*E*N = 262144   (later reused for Hw2)
#define WS_EDGEF  794688     // B*E*D = 131072
#define WS_ETYPE  925760     // B*E*T = 8192
#define WS_AGF    933952     // B*N*3D = 196608
#define WS_Q2     1130560    // B*N*D = 65536
#define WS_K2     1196096    // 65536
#define WS_V2     1261632    // 65536
// total 1327168 floats = 5.31 MB

__device__ inline unsigned rotl32(unsigned x, int d){ return (x<<d)|(x>>(32-d)); }

__device__ inline float bits_to_gumbel(unsigned bits){
  float f = __uint_as_float((bits>>9)|0x3f800000u) - 1.0f;
  const float minv = 1e-6f;
  const float maxv = 1.0f - 1e-6f;
  float u = f*(maxv-minv) + minv;
  u = fmaxf(minv, u);
  return -logf(-logf(u));
}

// K1: threefry2x32-20 gumbel noise (matches jax.random.uniform(key(42),(2,512,8)))
// plus c0 = relu(b1)@W2 + b2 (second-MLP value at zero input)
__global__ void gumbel_kernel(float* g, float* c0, const float* w_b1,
                              const float* w_W2, const float* w_b2){
  int j = blockIdx.x*blockDim.x + threadIdx.x;
  if (j < 4096) {
    const unsigned k0=0u, k1=42u;
    const unsigned ks2 = k0^k1^0x1BD11BDAu;
    unsigned x0 = (unsigned)j, x1 = (unsigned)j + 4096u;
    const int r0[4]={13,15,26,6}, r1[4]={17,29,16,24};
    x0 += k0; x1 += k1;
    #pragma unroll
    for(int i=0;i<4;i++){ x0+=x1; x1=rotl32(x1,r0[i]); x1^=x0; }
    x0+=k1; x1+=ks2+1u;
    #pragma unroll
    for(int i=0;i<4;i++){ x0+=x1; x1=rotl32(x1,r1[i]); x1^=x0; }
    x0+=ks2; x1+=k0+2u;
    #pragma unroll
    for(int i=0;i<4;i++){ x0+=x1; x1=rotl32(x1,r0[i]); x1^=x0; }
    x0+=k0; x1+=k1+3u;
    #pragma unroll
    for(int i=0;i<4;i++){ x0+=x1; x1=rotl32(x1,r1[i]); x1^=x0; }
    x0+=k1; x1+=ks2+4u;
    #pragma unroll
    for(int i=0;i<4;i++){ x0+=x1; x1=rotl32(x1,r0[i]); x1^=x0; }
    x0+=ks2; x1+=k0+5u;
    g[j]        = bits_to_gumbel(x0);
    g[j+4096]   = bits_to_gumbel(x1);
  }
  if (blockIdx.x==0 && threadIdx.x==0){
    float s = 0.f;
    for (int h=0;h<HDIM;h++) s += fmaxf(w_b1[h],0.f)*w_W2[h];
    c0[0] = s + w_b2[0];
  }
}

// K2: ef_init[b,e,:] = sum_n H*af ; edge_type[b,e,:] = sum_n H*at
// compact-then-stream: H row values are {0,1}; build compact index list.
__global__ void incidence_kernel(const float* Hm, const float* af, const float* at,
                                 float* ef0, float* etype){
  __shared__ int ecomp[NN];
  __shared__ int wcnt[2];
  int be = blockIdx.x;
  int d  = threadIdx.x;           // 128 (2 waves)
  int b  = be / EE;
  int lane = d & 63, wid = d >> 6;
  const float* Hrow = Hm + (size_t)be*NN;
  int total = 0;
  #pragma unroll
  for (int p=0;p<2;p++){
    int n = p*128 + d;
    bool pred = (Hrow[n] != 0.f);
    unsigned long long mask = __ballot(pred);
    if (lane==0) wcnt[wid] = __popcll(mask);
    int off = __popcll(mask & ((1ull<<lane)-1ull));
    __syncthreads();
    int wb = total + (wid==1 ? wcnt[0] : 0);
    if (pred) ecomp[wb+off] = n;
    total += wcnt[0]+wcnt[1];
    __syncthreads();
  }
  float acc = 0.f, acct = 0.f;
  for (int i=0;i<total;i++){
    int n = ecomp[i];
    acc += af[((size_t)b*NN+n)*DD + d];
    if (d < TT) acct += at[((size_t)b*NN+n)*TT + d];
  }
  ef0[(size_t)be*DD+d] = acc;
  if (d < TT) etype[(size_t)be*TT+d] = acct;
}

// K3: dst[row,h] = src[row,:]@W(128x256 slice) + bias[h]
__global__ void rowmlp_kernel(const float* src, const float* W, const float* bias, float* dst){
  __shared__ float s[DD];
  int row = blockIdx.x;
  int h = threadIdx.x;            // 256
  if (h < DD) s[h] = src[(size_t)row*DD + h];
  __syncthreads();
  float acc = bias ? bias[h] : 0.f;
  #pragma unroll 8
  for (int i=0;i<DD;i++) acc += s[i]*W[(size_t)i*HDIM + h];
  dst[(size_t)row*HDIM + h] = acc;
}

// K4: ew = sum_h relu(U1+V)*W2 + b2 ; Hw = softmax(ew*H, axis=n)*H
__global__ void ew_softmax_kernel(const float* U1, const float* Vm, const float* Hm,
                                  const float* w_W2, const float* w_b2, float* Hw){
  __shared__ float u[HDIM];
  __shared__ float w2[HDIM];
  __shared__ float red[256];
  int be = blockIdx.x;
  int b = be / EE;
  int n = threadIdx.x;            // 256
  u[n]  = U1[(size_t)be*HDIM + n];
  w2[n] = w_W2[n];
  __syncthreads();
  const float4* Vrow = (const float4*)(Vm + ((size_t)b*NN + n)*HDIM);
  float acc = 0.f;
  #pragma unroll 4
  for (int i=0;i<HDIM/4;i++){
    float4 v = Vrow[i];
    acc += fmaxf(u[4*i+0]+v.x,0.f)*w2[4*i+0];
    acc += fmaxf(u[4*i+1]+v.y,0.f)*w2[4*i+1];
    acc += fmaxf(u[4*i+2]+v.z,0.f)*w2[4*i+2];
    acc += fmaxf(u[4*i+3]+v.w,0.f)*w2[4*i+3];
  }
  float ew = acc + w_b2[0];
  float hv = Hm[(size_t)be*NN + n];
  float x = (hv != 0.f) ? ew : 0.f;
  red[n] = x; __syncthreads();
  for (int s=128;s>0;s>>=1){ if (n<s) red[n]=fmaxf(red[n],red[n+s]); __syncthreads(); }
  float m = red[0]; __syncthreads();
  float p = expf(x - m);
  red[n] = p; __syncthreads();
  for (int s=128;s>0;s>>=1){ if (n<s) red[n]+=red[n+s]; __syncthreads(); }
  float denom = red[0];
  Hw[(size_t)be*NN+n] = (hv!=0.f) ? p/denom : 0.f;
}

// K5: out[b,e,:] = sum_n Wgt[b,e,n]*af[b,n,:]  (compact-then-stream)
__global__ void aggregate_kernel(const float* Wgt, const float* af, float* outp){
  __shared__ int   ecomp[NN];
  __shared__ float wcomp[NN];
  __shared__ int wcnt[2];
  int be = blockIdx.x; int d = threadIdx.x; int b = be/EE;   // 128 threads
  int lane = d & 63, wid = d >> 6;
  const float* wrow = Wgt + (size_t)be*NN;
  int total = 0;
  #pragma unroll
  for (int p=0;p<2;p++){
    int n = p*128 + d;
    float w = wrow[n];
    bool pred = (w != 0.f);
    unsigned long long mask = __ballot(pred);
    if (lane==0) wcnt[wid] = __popcll(mask);
    int off = __popcll(mask & ((1ull<<lane)-1ull));
    __syncthreads();
    int wb = total + (wid==1 ? wcnt[0] : 0);
    if (pred){ ecomp[wb+off] = n; wcomp[wb+off] = w; }
    total += wcnt[0]+wcnt[1];
    __syncthreads();
  }
  float acc = 0.f;
  for (int i=0;i<total;i++){
    acc += wcomp[i]*af[((size_t)b*NN+ecomp[i])*DD + d];
  }
  outp[(size_t)be*DD + d] = acc;
}

// K6: typed edge embedding: logits/factor MLPs, gumbel softmax, ete = (f*dist)@type_emb
__global__ void type_kernel(const float* edgef, const float* etype, const float* g,
                            const float* d_W1, const float* d_b1, const float* d_W2, const float* d_b2,
                            const float* f_W1, const float* f_b1, const float* f_W2, const float* f_b2,
                            const float* type_emb, float* ete){
  __shared__ float et[DD+TT];
  __shared__ float hd_[HDIM];
  __shared__ float red[256];
  __shared__ float w2s[HDIM*KK];
  __shared__ float z[KK];
  __shared__ float pz[KK];
  __shared__ float fd[KK];
  __shared__ float factor_s;
  int be = blockIdx.x; int t = threadIdx.x;   // 256
  if (t < DD) et[t] = edgef[(size_t)be*DD+t];
  else if (t < DD+TT) et[t] = etype[(size_t)be*TT + (t-DD)];
  for (int i=t;i<HDIM*KK;i+=256) w2s[i] = d_W2[i];
  __syncthreads();
  float ad = d_b1[t], afv = f_b1[t];
  for (int i=0;i<DD+TT;i++){
    float x = et[i];
    ad  += x*d_W1[(size_t)i*HDIM+t];
    afv += x*f_W1[(size_t)i*HDIM+t];
  }
  hd_[t] = fmaxf(ad, 0.f);
  float hfr = fmaxf(afv, 0.f);
  red[t] = hfr * f_W2[t]; __syncthreads();
  for (int s=128;s>0;s>>=1){ if (t<s) red[t]+=red[t+s]; __syncthreads(); }
  if (t==0) factor_s = 1.f/(1.f+expf(-(red[0]+f_b2[0])));
  __syncthreads();
  // logits: all 256 threads; k = t&7, j = t>>3 (32 j-groups)
  {
    int k = t & 7, j = t >> 3;
    float partial = 0.f;
    #pragma unroll 4
    for (int h=j; h<HDIM; h+=32) partial += hd_[h]*w2s[h*KK + k];
    red[t] = partial; __syncthreads();          // red[j*8+k]
    for (int s=16;s>0;s>>=1){
      if (j < s) red[j*8+k] += red[(j+s)*8+k];
      __syncthreads();
    }
    if (t < KK) z[t] = (red[t] + d_b2[t] + g[(size_t)be*KK + t]) * 2.0f;  // /tau
  }
  __syncthreads();
  if (t < KK){
    float m = z[0];
    for (int k=1;k<KK;k++) m = fmaxf(m, z[k]);
    pz[t] = expf(z[t]-m);
  }
  __syncthreads();
  if (t < KK){
    float s = 0.f;
    for (int k=0;k<KK;k++) s += pz[k];
    fd[t] = factor_s * pz[t]/s;
  }
  __syncthreads();
  if (t < DD){
    float acc=0.f;
    #pragma unroll
    for (int k=0;k<KK;k++) acc += fd[k]*type_emb[(size_t)k*DD+t];
    ete[(size_t)be*DD+t]=acc;
  }
}

// K8: raw2 (masked MLP, c0 for H=0), leaky relu, full softmax over n, *H
__global__ void hw2_softmax_kernel(const float* U2, const float* Vm, const float* Hm,
                                   const float* w_W2, const float* w_b2, const float* c0p,
                                   float* Hw2){
  __shared__ float u[HDIM];
  __shared__ float w2[HDIM];
  __shared__ float red[256];
  int be = blockIdx.x; int b = be/EE; int n = threadIdx.x;
  u[n]  = U2[(size_t)be*HDIM+n];
  w2[n] = w_W2[n];
  __syncthreads();
  float hv = Hm[(size_t)be*NN+n];
  float raw;
  if (hv != 0.f){
    const float4* Vrow = (const float4*)(Vm + ((size_t)b*NN+n)*HDIM);
    float acc=0.f;
    #pragma unroll 4
    for (int i=0;i<HDIM/4;i++){
      float4 v=Vrow[i];
      acc += fmaxf(u[4*i+0]+v.x,0.f)*w2[4*i+0];
      acc += fmaxf(u[4*i+1]+v.y,0.f)*w2[4*i+1];
      acc += fmaxf(u[4*i+2]+v.z,0.f)*w2[4*i+2];
      acc += fmaxf(u[4*i+3]+v.w,0.f)*w2[4*i+3];
    }
    raw = acc + w_b2[0];
  } else {
    raw = c0p[0];
  }
  float x = raw>0.f ? raw : 0.01f*raw;     // leaky relu
  red[n]=x; __syncthreads();
  for (int s=128;s>0;s>>=1){ if (n<s) red[n]=fmaxf(red[n],red[n+s]); __syncthreads(); }
  float m = red[0]; __syncthreads();
  float p = expf(x-m);
  red[n]=p; __syncthreads();
  for (int s=128;s>0;s>>=1){ if (n<s) red[n]+=red[n+s]; __syncthreads(); }
  float denom = red[0];
  Hw2[(size_t)be*NN+n] = (hv!=0.f) ? p/denom : 0.f;
}

// K9: msg[b,n,f] = sum_e Hw2[b,e,n]*[edgef|ete][b,e,f]; agent_feat = [msg, af]
// compact-then-stream over the ~10%-dense Hw2 column.
__global__ void msg_kernel(const float* Hw2, const float* edgef, const float* ete,
                           const float* af, float* agf){
  __shared__ int   ecomp[EE];
  __shared__ float wcomp[EE];
  __shared__ int wcnt[4];
  int bn = blockIdx.x; int b = bn/NN; int n = bn%NN; int f = threadIdx.x; // 256 (4 waves)
  int lane = f & 63, wid = f >> 6;
  int total = 0;
  #pragma unroll
  for (int p=0;p<2;p++){
    int e = p*256 + f;
    float w = Hw2[((size_t)b*EE+e)*NN + n];
    bool pred = (w != 0.f);
    unsigned long long mask = __ballot(pred);
    if (lane==0) wcnt[wid] = __popcll(mask);
    int off = __popcll(mask & ((1ull<<lane)-1ull));
    __syncthreads();
    int wb = total;
    for (int ww=0; ww<wid; ww++) wb += wcnt[ww];
    if (pred){ ecomp[wb+off] = e; wcomp[wb+off] = w; }
    total += wcnt[0]+wcnt[1]+wcnt[2]+wcnt[3];
    __syncthreads();
  }
  float acc = 0.f;
  const float* srcbase = (f < DD) ? (edgef + (size_t)b*EE*DD + f)
                                  : (ete   + (size_t)b*EE*DD + (f-DD));
  for (int i=0;i<total;i++){
    acc += wcomp[i] * srcbase[(size_t)ecomp[i]*DD];
  }
  agf[(size_t)bn*(3*DD)+f] = acc;
  if (f < DD) agf[(size_t)bn*(3*DD) + 2*DD + f] = af[(size_t)bn*DD + f];
}

// K10a: q2 = (agf@q_W+q_b)@iq_W+iq_b
__global__ void q2_kernel(const float* agf, const float* q_W, const float* q_b,
                          const float* iq_W, const float* iq_b, float* q2){
  __shared__ float row[3*DD];
  __shared__ float Qs[DD];
  int bn = blockIdx.x; int d = threadIdx.x; // 128
  for (int i=d;i<3*DD;i+=DD) row[i]=agf[(size_t)bn*3*DD+i];
  __syncthreads();
  float q = q_b[d];
  #pragma unroll 8
  for (int i=0;i<3*DD;i++) q += row[i]*q_W[(size_t)i*DD+d];
  Qs[d]=q; __syncthreads();
  float v = iq_b[d];
  #pragma unroll 8
  for (int i=0;i<DD;i++) v += Qs[i]*iq_W[(size_t)i*DD+d];
  q2[(size_t)bn*DD+d]=v;
}

// K10b: k2, v2 from polyline features
__global__ void kv_kernel(const float* pf,
                          const float* k_W,const float* k_b,const float* ik_W,const float* ik_b,
                          const float* v_W,const float* v_b,const float* iv_W,const float* iv_b,
                          float* k2, float* v2){
  __shared__ float row[DD];
  __shared__ float tmp[DD];
  int bp=blockIdx.x; int d=threadIdx.x;   // 128
  row[d]=pf[(size_t)bp*DD+d]; __syncthreads();
  float kk=k_b[d];
  #pragma unroll 8
  for(int i=0;i<DD;i++) kk+=row[i]*k_W[(size_t)i*DD+d];
  tmp[d]=kk; __syncthreads();
  float kv=ik_b[d];
  #pragma unroll 8
  for(int i=0;i<DD;i++) kv+=tmp[i]*ik_W[(size_t)i*DD+d];
  k2[(size_t)bp*DD+d]=kv; __syncthreads();
  float vv=v_b[d];
  #pragma unroll 8
  for(int i=0;i<DD;i++) vv+=row[i]*v_W[(size_t)i*DD+d];
  tmp[d]=vv; __syncthreads();
  float v2v=iv_b[d];
  #pragma unroll 8
  for(int i=0;i<DD;i++) v2v+=tmp[i]*iv_W[(size_t)i*DD+d];
  v2[(size_t)bp*DD+d]=v2v;
}

// K10c: 4-head cross attention + output proj -> polyline_new
__global__ void attn_kernel(const float* q2, const float* k2, const float* v2,
                            const float* op_W, const float* op_b, float* pnew){
  __shared__ float qr[DD];
  __shared__ float att[4*PP];
  __shared__ float red[256];
  __shared__ float o_lds[DD];
  int bn = blockIdx.x; int b = bn/NN; int t = threadIdx.x; // 256 (= p index)
  if (t<DD) qr[t]=q2[(size_t)bn*DD+t];
  __syncthreads();
  const float scale = 0.17677669529663687f;  // 1/sqrt(32)
  const float* krow = k2 + ((size_t)b*PP + t)*DD;
  for (int h=0;h<4;h++){
    float s=0.f;
    #pragma unroll 8
    for (int j=0;j<32;j++) s += qr[h*32+j]*krow[h*32+j];
    att[h*PP+t]=s*scale;
  }
  __syncthreads();
  for (int h=0;h<4;h++){
    float x = att[h*PP+t];
    red[t]=x; __syncthreads();
    for (int s=128;s>0;s>>=1){ if(t<s) red[t]=fmaxf(red[t],red[t+s]); __syncthreads(); }
    float m=red[0]; __syncthreads();
    float p=expf(x-m);
    red[t]=p; __syncthreads();
    for (int s=128;s>0;s>>=1){ if(t<s) red[t]+=red[t+s]; __syncthreads(); }
    float dn=red[0]; __syncthreads();
    att[h*PP+t]=p/dn;
    __syncthreads();
  }
  if (t < DD){
    float acc=0.f; int h=t>>5;
    for (int p=0;p<PP;p++) acc += att[h*PP+p]*v2[((size_t)b*PP+p)*DD + t];
    o_lds[t]=acc;
  }
  __syncthreads();
  if (t < DD){
    float pn=op_b[t];
    #pragma unroll 8
    for (int i=0;i<DD;i++) pn += o_lds[i]*op_W[(size_t)i*DD+t];
    pnew[(size_t)bn*DD+t]=pn;
  }
}

// K11: agent_new = MLP([agf, pnew], o_*)
__global__ void final_kernel(const float* agf, const float* pnew,
                             const float* o_W1,const float* o_b1,
                             const float* o_W2,const float* o_b2, float* anew){
  __shared__ float x[4*DD];
  __shared__ float hid[HDIM];
  int bn=blockIdx.x; int t=threadIdx.x;  // 256
  x[t] = agf[(size_t)bn*3*DD+t];
  int i2 = t+256;
  x[i2] = (i2 < 3*DD) ? agf[(size_t)bn*3*DD+i2] : pnew[(size_t)bn*DD + (i2-3*DD)];
  __syncthreads();
  float acc=o_b1[t];
  #pragma unroll 8
  for (int i=0;i<4*DD;i++) acc += x[i]*o_W1[(size_t)i*HDIM+t];
  hid[t]=fmaxf(acc,0.f);
  __syncthreads();
  if (t<DD){
    float outv=o_b2[t];
    #pragma unroll 8
    for (int h=0;h<HDIM;h++) outv += hid[h]*o_W2[(size_t)h*DD+t];
    anew[(size_t)bn*DD+t]=outv;
  }
}

extern "C" void kernel_launch(void* const* d_in, const int* in_sizes, int n_in,
                              void* d_out, int out_size, void* d_ws, size_t ws_size,
                              hipStream_t stream) {
  const float* af       = (const float*)d_in[0];
  const float* at       = (const float*)d_in[1];
  const float* pf       = (const float*)d_in[2];
  const float* Hm       = (const float*)d_in[3];
  const float* type_emb = (const float*)d_in[4];
  const float* w_W1 = (const float*)d_in[5];
  const float* w_b1 = (const float*)d_in[6];
  const float* w_W2 = (const float*)d_in[7];
  const float* w_b2 = (const float*)d_in[8];
  const float* d_W1 = (const float*)d_in[9];
  const float* d_b1 = (const float*)d_in[10];
  const float* d_W2 = (const float*)d_in[11];
  const float* d_b2 = (const float*)d_in[12];
  const float* f_W1 = (const float*)d_in[13];
  const float* f_b1 = (const float*)d_in[14];
  const float* f_W2 = (const float*)d_in[15];
  const float* f_b2 = (const float*)d_in[16];
  const float* o_W1 = (const float*)d_in[17];
  const float* o_b1 = (const float*)d_in[18];
  const float* o_W2 = (const float*)d_in[19];
  const float* o_b2 = (const float*)d_in[20];
  const float* q_W  = (const float*)d_in[21];
  const float* q_b  = (const float*)d_in[22];
  const float* k_W  = (const float*)d_in[23];
  const float* k_b  = (const float*)d_in[24];
  const float* v_W  = (const float*)d_in[25];
  const float* v_b  = (const float*)d_in[26];
  const float* iq_W = (const float*)d_in[27];
  const float* iq_b = (const float*)d_in[28];
  const float* ik_W = (const float*)d_in[29];
  const float* ik_b = (const float*)d_in[30];
  const float* iv_W = (const float*)d_in[31];
  const float* iv_b = (const float*)d_in[32];
  const float* op_W = (const float*)d_in[33];
  const float* op_b = (const float*)d_in[34];

  float* ws   = (float*)d_ws;
  float* out  = (float*)d_out;
  float* anew = out;                 // (B,N,D)
  float* pnew = out + BB*NN*DD;      // (B,N,D)

  gumbel_kernel<<<16,256,0,stream>>>(ws+WS_G, ws+WS_C0, w_b1, w_W2, w_b2);
  incidence_kernel<<<BB*EE,128,0,stream>>>(Hm, af, at, ws+WS_EF0, ws+WS_ETYPE);
  rowmlp_kernel<<<BB*EE,256,0,stream>>>(ws+WS_EF0, w_W1,          w_b1,    ws+WS_U1);
  rowmlp_kernel<<<BB*NN,256,0,stream>>>(af,        w_W1 + DD*HDIM, nullptr, ws+WS_V);
  ew_softmax_kernel<<<BB*EE,256,0,stream>>>(ws+WS_U1, ws+WS_V, Hm, w_W2, w_b2, ws+WS_HW);
  aggregate_kernel<<<BB*EE,128,0,stream>>>(ws+WS_HW, af, ws+WS_EDGEF);
  type_kernel<<<BB*EE,256,0,stream>>>(ws+WS_EDGEF, ws+WS_ETYPE, ws+WS_G,
                                      d_W1,d_b1,d_W2,d_b2, f_W1,f_b1,f_W2,f_b2,
                                      type_emb, ws+WS_EF0 /*ete*/);
  rowmlp_kernel<<<BB*EE,256,0,stream>>>(ws+WS_EF0, w_W1, w_b1, ws+WS_U1 /*U2*/);
  hw2_softmax_kernel<<<BB*EE,256,0,stream>>>(ws+WS_U1, ws+WS_V, Hm, w_W2, w_b2,
                                             ws+WS_C0, ws+WS_HW /*Hw2*/);
  msg_kernel<<<BB*NN,256,0,stream>>>(ws+WS_HW, ws+WS_EDGEF, ws+WS_EF0, af, ws+WS_AGF);
  q2_kernel<<<BB*NN,128,0,stream>>>(ws+WS_AGF, q_W,q_b, iq_W,iq_b, ws+WS_Q2);
  kv_kernel<<<BB*PP,128,0,stream>>>(pf, k_W,k_b, ik_W,ik_b, v_W,v_b, iv_W,iv_b,
                                    ws+WS_K2, ws+WS_V2);
  attn_kernel<<<BB*NN,256,0,stream>>>(ws+WS_Q2, ws+WS_K2, ws+WS_V2, op_W, op_b, pnew);
  final_kernel<<<BB*NN,256,0,stream>>>(ws+WS_AGF, pnew, o_W1,o_b1,o_W2,o_b2, anew);
}